// Round 1
// baseline (350.268 us; speedup 1.0000x reference)
//
#include <hip/hip_runtime.h>
#include <cstddef>
#include <cstdint>

// Problem constants (B,N,H) = (8,256,64)
constexpr int Bv = 8, Nv = 256, Hv = 64;
constexpr int ROWS  = Bv * Nv;           // 2048
constexpr float INV_EDGE_CNT = 1.0f / (8.0f * 256.0f * 256.0f);
constexpr float INV_NODE_CNT = 1.0f / 2048.0f;
constexpr float EPSBN = 1e-5f;

// ws layout (float offsets)
constexpr size_t WS_VXE  = 0;          // [2048*64]  Vxe = x@VeW^T + b
constexpr size_t WS_UX   = 131072;     // [2048*64]  Ux
constexpr size_t WS_VXN  = 262144;     // [2048*64]  Vxn
constexpr size_t WS_AGG  = 393216;     // [2048*64]  sum_j gate*Vxn
constexpr size_t WS_ESUM = 524288;     // [64] channel sums of e_tmp
constexpr size_t WS_ESQ  = 524352;     // [64] channel sumsq of e_tmp

#define DOT4(acc, a, b) \
  acc = fmaf((a).x, (b).x, fmaf((a).y, (b).y, fmaf((a).z, (b).z, fmaf((a).w, (b).w, acc))))

// ---------------------------------------------------------------------------
// Small linears: Vxe / Ux / Vxn  (2048 rows x 64 ch each)
__global__ __launch_bounds__(256) void k_lin(
    const float* __restrict__ x,
    const float* __restrict__ VeW, const float* __restrict__ Veb,
    const float* __restrict__ UnW, const float* __restrict__ Unb,
    const float* __restrict__ VnW, const float* __restrict__ Vnb,
    float* __restrict__ ws)
{
  int idx = blockIdx.x * 256 + threadIdx.x;   // 131072 total
  int r = idx >> 6, o = idx & 63;
  const float4* x4  = (const float4*)(x + (size_t)r * 64);
  const float4* w14 = (const float4*)(VeW + (size_t)o * 64);
  const float4* w24 = (const float4*)(UnW + (size_t)o * 64);
  const float4* w34 = (const float4*)(VnW + (size_t)o * 64);
  float a1 = 0.f, a2 = 0.f, a3 = 0.f;
#pragma unroll
  for (int h = 0; h < 16; ++h) {
    float4 xv = x4[h];
    float4 v1 = w14[h]; DOT4(a1, xv, v1);
    float4 v2 = w24[h]; DOT4(a2, xv, v2);
    float4 v3 = w34[h]; DOT4(a3, xv, v3);
  }
  ws[WS_VXE + idx] = a1 + Veb[o];
  ws[WS_UX  + idx] = a2 + Unb[o];
  ws[WS_VXN + idx] = a3 + Vnb[o];
}

// ---------------------------------------------------------------------------
// Pass A: per (b,i), compute e_tmp over all (j,o); accumulate channel
// sum/sumsq and agg[b,i,o] = sum_j sigmoid(e_tmp)*Vxn[b,j,o].
__global__ __launch_bounds__(256) void k_edgeA(
    const float* __restrict__ e,
    const float* __restrict__ UeW, const float* __restrict__ Ueb,
    float* __restrict__ ws)
{
  __shared__ __align__(16) float wL[64 * 64];
  __shared__ __align__(16) float eL[64 * 64];

  const float* Vxe = ws + WS_VXE;
  const float* Vxn = ws + WS_VXN;
  float* agg   = ws + WS_AGG;
  float* esum  = ws + WS_ESUM;
  float* esumq = ws + WS_ESQ;

  const int tid = threadIdx.x;
  const int bi  = blockIdx.x;               // b*256 + i
  const int rowB = bi & ~255;               // b*256
  const float* eBase = e + (size_t)bi * (Nv * Hv);

  // stage Ue_W swizzled: dst = o*64 + (h4 ^ ((o&7)<<2))
  {
    const float4* src = (const float4*)UeW;
#pragma unroll
    for (int k = 0; k < 4; ++k) {
      int g = tid + 256 * k;                // float4 index 0..1023
      float4 v = src[g];
      int o = g >> 4, h4 = (g & 15) << 2;
      *(float4*)(wL + o * 64 + (h4 ^ ((o & 7) << 2))) = v;
    }
  }

  const int jt = tid & 15, ot = tid >> 4;
  const int o0 = ot << 2;
  const int swzE = (jt & 7) << 2;

  float4 ueb  = *(const float4*)(Ueb + o0);
  float4 vxei = *(const float4*)(Vxe + (size_t)bi * 64 + o0);

  float sSum[4] = {0, 0, 0, 0};
  float sSq[4]  = {0, 0, 0, 0};
  float sAgg[4] = {0, 0, 0, 0};

  const int eR0 = (jt + 0)  * 64;
  const int eR1 = (jt + 16) * 64;
  const int eR2 = (jt + 32) * 64;
  const int eR3 = (jt + 48) * 64;
  const int wR[4]   = {(o0 + 0) * 64, (o0 + 1) * 64, (o0 + 2) * 64, (o0 + 3) * 64};
  const int swzW[4] = {((o0 + 0) & 7) << 2, ((o0 + 1) & 7) << 2,
                       ((o0 + 2) & 7) << 2, ((o0 + 3) & 7) << 2};

  for (int chnk = 0; chnk < 4; ++chnk) {
    __syncthreads();
    // stage 64 e-rows, swizzled
    {
      const float4* src = (const float4*)(eBase + (size_t)chnk * 64 * 64);
#pragma unroll
      for (int k = 0; k < 4; ++k) {
        int g = tid + 256 * k;
        float4 v = src[g];
        int j = g >> 4, h4 = (g & 15) << 2;
        *(float4*)(eL + j * 64 + (h4 ^ ((j & 7) << 2))) = v;
      }
    }
    __syncthreads();

    float acc[4][4] = {};
#pragma unroll
    for (int h4 = 0; h4 < 64; h4 += 4) {
      const int he = h4 ^ swzE;
      float4 ev0 = *(const float4*)(eL + eR0 + he);
      float4 ev1 = *(const float4*)(eL + eR1 + he);
      float4 ev2 = *(const float4*)(eL + eR2 + he);
      float4 ev3 = *(const float4*)(eL + eR3 + he);
#pragma unroll
      for (int c = 0; c < 4; ++c) {
        float4 wv = *(const float4*)(wL + wR[c] + (h4 ^ swzW[c]));
        DOT4(acc[0][c], ev0, wv);
        DOT4(acc[1][c], ev1, wv);
        DOT4(acc[2][c], ev2, wv);
        DOT4(acc[3][c], ev3, wv);
      }
    }

    // epilogue: e_tmp = acc + Ue_b + Vxe_i + Vxe_j ; stats + gated agg
#pragma unroll
    for (int d = 0; d < 4; ++d) {
      int j = chnk * 64 + jt + 16 * d;
      float4 vj = *(const float4*)(Vxe + (size_t)(rowB + j) * 64 + o0);
      float4 vn = *(const float4*)(Vxn + (size_t)(rowB + j) * 64 + o0);
      float tj[4] = {vj.x, vj.y, vj.z, vj.w};
      float tn[4] = {vn.x, vn.y, vn.z, vn.w};
      float ub[4] = {ueb.x, ueb.y, ueb.z, ueb.w};
      float vi[4] = {vxei.x, vxei.y, vxei.z, vxei.w};
#pragma unroll
      for (int c = 0; c < 4; ++c) {
        float t = acc[d][c] + ub[c] + vi[c] + tj[c];
        sSum[c] += t;
        sSq[c]   = fmaf(t, t, sSq[c]);
        float sg = 1.0f / (1.0f + __expf(-t));
        sAgg[c]  = fmaf(sg, tn[c], sAgg[c]);
      }
    }
  }

  // reduce across the 16 jt lanes (butterfly within each 16-lane group)
#pragma unroll
  for (int m = 1; m < 16; m <<= 1) {
#pragma unroll
    for (int c = 0; c < 4; ++c) {
      sSum[c] += __shfl_xor(sSum[c], m);
      sSq[c]  += __shfl_xor(sSq[c],  m);
      sAgg[c] += __shfl_xor(sAgg[c], m);
    }
  }
  if (jt == 0) {
    *(float4*)(agg + (size_t)bi * 64 + o0) =
        make_float4(sAgg[0], sAgg[1], sAgg[2], sAgg[3]);
#pragma unroll
    for (int c = 0; c < 4; ++c) {
      atomicAdd(&esum[o0 + c],  sSum[c]);
      atomicAdd(&esumq[o0 + c], sSq[c]);
    }
  }
}

// ---------------------------------------------------------------------------
// Node path: x_tmp = Ux + agg ; BN over (B,N) per channel ; relu + residual
__global__ __launch_bounds__(256) void k_node(
    const float* __restrict__ x,
    const float* __restrict__ bnng, const float* __restrict__ bnnb,
    const float* __restrict__ ws, float* __restrict__ xOut)
{
  const int c = blockIdx.x;      // channel
  const int tid = threadIdx.x;
  const float* Ux  = ws + WS_UX;
  const float* agg = ws + WS_AGG;

  float v[8];
  float s = 0.f, q = 0.f;
#pragma unroll
  for (int k = 0; k < 8; ++k) {
    int r = tid + 256 * k;
    float t = Ux[(size_t)r * 64 + c] + agg[(size_t)r * 64 + c];
    v[k] = t;
    s += t;
    q = fmaf(t, t, q);
  }
#pragma unroll
  for (int m = 1; m < 64; m <<= 1) {
    s += __shfl_xor(s, m);
    q += __shfl_xor(q, m);
  }
  __shared__ float ss[4], qq[4];
  int w = tid >> 6;
  if ((tid & 63) == 0) { ss[w] = s; qq[w] = q; }
  __syncthreads();
  float S = ss[0] + ss[1] + ss[2] + ss[3];
  float Q = qq[0] + qq[1] + qq[2] + qq[3];
  float mean = S * INV_NODE_CNT;
  float var  = Q * INV_NODE_CNT - mean * mean;
  float scv = rsqrtf(var + EPSBN) * bnng[c];
  float shv = bnnb[c] - mean * scv;
#pragma unroll
  for (int k = 0; k < 8; ++k) {
    int r = tid + 256 * k;
    float y = fmaf(v[k], scv, shv);
    xOut[(size_t)r * 64 + c] = fmaxf(y, 0.f) + x[(size_t)r * 64 + c];
  }
}

// ---------------------------------------------------------------------------
// Pass C: recompute e_tmp, apply BN + relu + residual, write e_new
__global__ __launch_bounds__(256) void k_edgeC(
    const float* __restrict__ e,
    const float* __restrict__ UeW, const float* __restrict__ Ueb,
    const float* __restrict__ bneg, const float* __restrict__ bneb,
    const float* __restrict__ ws, float* __restrict__ eOut)
{
  __shared__ __align__(16) float wL[64 * 64];
  __shared__ __align__(16) float eL[64 * 64];
  __shared__ float scaleL[64], shiftL[64];

  const float* Vxe   = ws + WS_VXE;
  const float* esum  = ws + WS_ESUM;
  const float* esumq = ws + WS_ESQ;

  const int tid = threadIdx.x;
  const int bi  = blockIdx.x;
  const int rowB = bi & ~255;
  const float* eBase = e + (size_t)bi * (Nv * Hv);

  if (tid < 64) {
    float mean = esum[tid] * INV_EDGE_CNT;
    float var  = esumq[tid] * INV_EDGE_CNT - mean * mean;
    float sc = rsqrtf(var + EPSBN) * bneg[tid];
    scaleL[tid] = sc;
    shiftL[tid] = bneb[tid] - mean * sc;
  }
  {
    const float4* src = (const float4*)UeW;
#pragma unroll
    for (int k = 0; k < 4; ++k) {
      int g = tid + 256 * k;
      float4 v = src[g];
      int o = g >> 4, h4 = (g & 15) << 2;
      *(float4*)(wL + o * 64 + (h4 ^ ((o & 7) << 2))) = v;
    }
  }

  const int jt = tid & 15, ot = tid >> 4;
  const int o0 = ot << 2;
  const int swzE = (jt & 7) << 2;

  float4 ueb  = *(const float4*)(Ueb + o0);
  float4 vxei = *(const float4*)(Vxe + (size_t)bi * 64 + o0);

  const int eR0 = (jt + 0)  * 64;
  const int eR1 = (jt + 16) * 64;
  const int eR2 = (jt + 32) * 64;
  const int eR3 = (jt + 48) * 64;
  const int wR[4]   = {(o0 + 0) * 64, (o0 + 1) * 64, (o0 + 2) * 64, (o0 + 3) * 64};
  const int swzW[4] = {((o0 + 0) & 7) << 2, ((o0 + 1) & 7) << 2,
                       ((o0 + 2) & 7) << 2, ((o0 + 3) & 7) << 2};

  __syncthreads();   // scaleL/shiftL + wL ready
  float sc[4] = {scaleL[o0], scaleL[o0 + 1], scaleL[o0 + 2], scaleL[o0 + 3]};
  float sh[4] = {shiftL[o0], shiftL[o0 + 1], shiftL[o0 + 2], shiftL[o0 + 3]};
  float ub[4] = {ueb.x, ueb.y, ueb.z, ueb.w};
  float vi[4] = {vxei.x, vxei.y, vxei.z, vxei.w};

  for (int chnk = 0; chnk < 4; ++chnk) {
    __syncthreads();
    {
      const float4* src = (const float4*)(eBase + (size_t)chnk * 64 * 64);
#pragma unroll
      for (int k = 0; k < 4; ++k) {
        int g = tid + 256 * k;
        float4 v = src[g];
        int j = g >> 4, h4 = (g & 15) << 2;
        *(float4*)(eL + j * 64 + (h4 ^ ((j & 7) << 2))) = v;
      }
    }
    __syncthreads();

    float acc[4][4] = {};
#pragma unroll
    for (int h4 = 0; h4 < 64; h4 += 4) {
      const int he = h4 ^ swzE;
      float4 ev0 = *(const float4*)(eL + eR0 + he);
      float4 ev1 = *(const float4*)(eL + eR1 + he);
      float4 ev2 = *(const float4*)(eL + eR2 + he);
      float4 ev3 = *(const float4*)(eL + eR3 + he);
#pragma unroll
      for (int c = 0; c < 4; ++c) {
        float4 wv = *(const float4*)(wL + wR[c] + (h4 ^ swzW[c]));
        DOT4(acc[0][c], ev0, wv);
        DOT4(acc[1][c], ev1, wv);
        DOT4(acc[2][c], ev2, wv);
        DOT4(acc[3][c], ev3, wv);
      }
    }

#pragma unroll
    for (int d = 0; d < 4; ++d) {
      int jl = jt + 16 * d;                   // row within chunk
      int j  = chnk * 64 + jl;
      float4 vj = *(const float4*)(Vxe + (size_t)(rowB + j) * 64 + o0);
      // residual e value from the staged (swizzled) LDS tile
      float4 eo = *(const float4*)(eL + jl * 64 + (o0 ^ swzE));
      float tj[4] = {vj.x, vj.y, vj.z, vj.w};
      float er[4] = {eo.x, eo.y, eo.z, eo.w};
      float out[4];
#pragma unroll
      for (int c = 0; c < 4; ++c) {
        float t = acc[d][c] + ub[c] + vi[c] + tj[c];
        float y = fmaf(t, sc[c], sh[c]);
        out[c] = fmaxf(y, 0.f) + er[c];
      }
      *(float4*)(eOut + (size_t)bi * (Nv * Hv) + (size_t)j * 64 + o0) =
          make_float4(out[0], out[1], out[2], out[3]);
    }
  }
}

// ---------------------------------------------------------------------------
extern "C" void kernel_launch(void* const* d_in, const int* in_sizes, int n_in,
                              void* d_out, int out_size, void* d_ws, size_t ws_size,
                              hipStream_t stream)
{
  const float* x    = (const float*)d_in[0];
  const float* e    = (const float*)d_in[1];
  const float* UeW  = (const float*)d_in[2];
  const float* Ueb  = (const float*)d_in[3];
  const float* VeW  = (const float*)d_in[4];
  const float* Veb  = (const float*)d_in[5];
  const float* UnW  = (const float*)d_in[6];
  const float* Unb  = (const float*)d_in[7];
  const float* VnW  = (const float*)d_in[8];
  const float* Vnb  = (const float*)d_in[9];
  const float* bneg = (const float*)d_in[10];
  const float* bneb = (const float*)d_in[11];
  const float* bnng = (const float*)d_in[12];
  const float* bnnb = (const float*)d_in[13];

  float* ws   = (float*)d_ws;
  float* xOut = (float*)d_out;
  float* eOut = (float*)d_out + (size_t)ROWS * Hv;   // after x_new (131072)

  // zero only the atomic accumulators (128 floats)
  hipMemsetAsync(ws + WS_ESUM, 0, 128 * sizeof(float), stream);

  k_lin<<<512, 256, 0, stream>>>(x, VeW, Veb, UnW, Unb, VnW, Vnb, ws);
  k_edgeA<<<ROWS, 256, 0, stream>>>(e, UeW, Ueb, ws);
  k_node<<<Hv, 256, 0, stream>>>(x, bnng, bnnb, ws, xOut);
  k_edgeC<<<ROWS, 256, 0, stream>>>(e, UeW, Ueb, bneg, bneb, ws, eOut);
}

// Round 2
// 204.322 us; speedup vs baseline: 1.7143x; 1.7143x over previous
//
#include <hip/hip_runtime.h>
#include <cstddef>
#include <cstdint>

// Problem constants (B,N,H) = (8,256,64)
constexpr int Bv = 8, Nv = 256, Hv = 64;
constexpr int ROWS = Bv * Nv;            // 2048
constexpr float INV_EDGE_CNT = 1.0f / (8.0f * 256.0f * 256.0f);
constexpr float INV_NODE_CNT = 1.0f / 2048.0f;
constexpr float EPSBN = 1e-5f;

// ws layout (float offsets)
constexpr size_t WS_VXE  = 0;          // [2048*64]
constexpr size_t WS_UX   = 131072;     // [2048*64]
constexpr size_t WS_VXN  = 262144;     // [2048*64]
constexpr size_t WS_AGG  = 393216;     // [2048*64]
constexpr size_t WS_ESUM = 524288;     // [64]
constexpr size_t WS_ESQ  = 524352;     // [64]

typedef __bf16 bf16x8 __attribute__((ext_vector_type(8)));
typedef float  f32x4  __attribute__((ext_vector_type(4)));

__device__ __forceinline__ float4 ld4(const float* p) {
  return *reinterpret_cast<const float4*>(p);
}

__device__ __forceinline__ bf16x8 cvt8(float4 a, float4 b) {
  bf16x8 r;
  r[0] = (__bf16)a.x; r[1] = (__bf16)a.y; r[2] = (__bf16)a.z; r[3] = (__bf16)a.w;
  r[4] = (__bf16)b.x; r[5] = (__bf16)b.y; r[6] = (__bf16)b.z; r[7] = (__bf16)b.w;
  return r;
}

#define DOT4(acc, a, b) \
  acc = fmaf((a).x, (b).x, fmaf((a).y, (b).y, fmaf((a).z, (b).z, fmaf((a).w, (b).w, acc))))

// ---------------------------------------------------------------------------
// Small linears: Vxe / Ux / Vxn  (2048 rows x 64 ch each)
__global__ __launch_bounds__(256) void k_lin(
    const float* __restrict__ x,
    const float* __restrict__ VeW, const float* __restrict__ Veb,
    const float* __restrict__ UnW, const float* __restrict__ Unb,
    const float* __restrict__ VnW, const float* __restrict__ Vnb,
    float* __restrict__ ws)
{
  int idx = blockIdx.x * 256 + threadIdx.x;   // 131072 total
  int r = idx >> 6, o = idx & 63;
  const float4* x4  = (const float4*)(x + (size_t)r * 64);
  const float4* w14 = (const float4*)(VeW + (size_t)o * 64);
  const float4* w24 = (const float4*)(UnW + (size_t)o * 64);
  const float4* w34 = (const float4*)(VnW + (size_t)o * 64);
  float a1 = 0.f, a2 = 0.f, a3 = 0.f;
#pragma unroll
  for (int h = 0; h < 16; ++h) {
    float4 xv = x4[h];
    float4 v1 = w14[h]; DOT4(a1, xv, v1);
    float4 v2 = w24[h]; DOT4(a2, xv, v2);
    float4 v3 = w34[h]; DOT4(a3, xv, v3);
  }
  ws[WS_VXE + idx] = a1 + Veb[o];
  ws[WS_UX  + idx] = a2 + Unb[o];
  ws[WS_VXN + idx] = a3 + Vnb[o];
}

// ---------------------------------------------------------------------------
// Pass A: MFMA e@UeW^T per (b,i); fused sigmoid-gate aggregation + BN stats.
// Wave w owns o-tile [16w,16w+16); all 256 j. No LDS, no barriers.
__global__ __launch_bounds__(256) void k_edgeA(
    const float* __restrict__ e,
    const float* __restrict__ UeW, const float* __restrict__ Ueb,
    float* __restrict__ ws)
{
  const int tid  = threadIdx.x;
  const int lane = tid & 63;
  const int w    = tid >> 6;            // wave id = o-tile
  const int bi   = blockIdx.x;          // b*256 + i
  const int rowB = bi & ~255;
  const int r16  = lane & 15;
  const int g    = lane >> 4;
  const int c    = w * 16 + r16;        // output channel (B/C col)

  // B fragments: lane holds W[c][8g..8g+7] (k0) and W[c][32+8g..+7] (k1)
  const float* wrow = UeW + (size_t)c * 64 + 8 * g;
  bf16x8 bF0 = cvt8(ld4(wrow),      ld4(wrow + 4));
  bf16x8 bF1 = cvt8(ld4(wrow + 32), ld4(wrow + 36));

  const float* Vxe = ws + WS_VXE;
  const float* Vxn = ws + WS_VXN;
  const float ueb  = Ueb[c];
  const float vxei = Vxe[(size_t)bi * 64 + c];

  // A base: lane reads e[bi][row=r16][h=8g..], advancing 16 rows per tile
  const float* eb = e + (size_t)bi * (Nv * Hv) + (size_t)r16 * 64 + 8 * g;

  float sSum = 0.f, sSq = 0.f, sAgg = 0.f;

  for (int jt = 0; jt < 16; ++jt) {
    const float* ep = eb + jt * (16 * 64);
    bf16x8 aF0 = cvt8(ld4(ep),      ld4(ep + 4));
    bf16x8 aF1 = cvt8(ld4(ep + 32), ld4(ep + 36));
    f32x4 acc = {0.f, 0.f, 0.f, 0.f};
    acc = __builtin_amdgcn_mfma_f32_16x16x32_bf16(aF0, bF0, acc, 0, 0, 0);
    acc = __builtin_amdgcn_mfma_f32_16x16x32_bf16(aF1, bF1, acc, 0, 0, 0);

    // C layout: col = lane&15 (=c), row = 4g + reg
    const int j0 = jt * 16 + 4 * g;
#pragma unroll
    for (int r = 0; r < 4; ++r) {
      const size_t jrow = (size_t)(rowB + j0 + r) * 64 + c;
      float vj = Vxe[jrow];
      float vn = Vxn[jrow];
      float t  = acc[r] + ueb + vxei + vj;
      sSum += t;
      sSq   = fmaf(t, t, sSq);
      float sg = 1.0f / (1.0f + __expf(-t));
      sAgg  = fmaf(sg, vn, sAgg);
    }
  }

  // reduce over g-groups (same channel c lives in lanes c, c+16, c+32, c+48)
  sSum += __shfl_xor(sSum, 16); sSq += __shfl_xor(sSq, 16); sAgg += __shfl_xor(sAgg, 16);
  sSum += __shfl_xor(sSum, 32); sSq += __shfl_xor(sSq, 32); sAgg += __shfl_xor(sAgg, 32);

  if (g == 0) {
    ws[WS_AGG + (size_t)bi * 64 + c] = sAgg;
    atomicAdd(&ws[WS_ESUM + c], sSum);
    atomicAdd(&ws[WS_ESQ  + c], sSq);
  }
}

// ---------------------------------------------------------------------------
// Node path: x_tmp = Ux + agg ; BN over (B,N) per channel ; relu + residual
__global__ __launch_bounds__(256) void k_node(
    const float* __restrict__ x,
    const float* __restrict__ bnng, const float* __restrict__ bnnb,
    const float* __restrict__ ws, float* __restrict__ xOut)
{
  const int c = blockIdx.x;
  const int tid = threadIdx.x;
  const float* Ux  = ws + WS_UX;
  const float* agg = ws + WS_AGG;

  float v[8];
  float s = 0.f, q = 0.f;
#pragma unroll
  for (int k = 0; k < 8; ++k) {
    int r = tid + 256 * k;
    float t = Ux[(size_t)r * 64 + c] + agg[(size_t)r * 64 + c];
    v[k] = t;
    s += t;
    q = fmaf(t, t, q);
  }
#pragma unroll
  for (int m = 1; m < 64; m <<= 1) {
    s += __shfl_xor(s, m);
    q += __shfl_xor(q, m);
  }
  __shared__ float ss[4], qq[4];
  int w = tid >> 6;
  if ((tid & 63) == 0) { ss[w] = s; qq[w] = q; }
  __syncthreads();
  float S = ss[0] + ss[1] + ss[2] + ss[3];
  float Q = qq[0] + qq[1] + qq[2] + qq[3];
  float mean = S * INV_NODE_CNT;
  float var  = Q * INV_NODE_CNT - mean * mean;
  float scv = rsqrtf(var + EPSBN) * bnng[c];
  float shv = bnnb[c] - mean * scv;
#pragma unroll
  for (int k = 0; k < 8; ++k) {
    int r = tid + 256 * k;
    float y = fmaf(v[k], scv, shv);
    xOut[(size_t)r * 64 + c] = fmaxf(y, 0.f) + x[(size_t)r * 64 + c];
  }
}

// ---------------------------------------------------------------------------
// Pass C: recompute e_tmp via MFMA, apply BN + relu + residual, write e_new
__global__ __launch_bounds__(256) void k_edgeC(
    const float* __restrict__ e,
    const float* __restrict__ UeW, const float* __restrict__ Ueb,
    const float* __restrict__ bneg, const float* __restrict__ bneb,
    const float* __restrict__ ws, float* __restrict__ eOut)
{
  const int tid  = threadIdx.x;
  const int lane = tid & 63;
  const int w    = tid >> 6;
  const int bi   = blockIdx.x;
  const int rowB = bi & ~255;
  const int r16  = lane & 15;
  const int g    = lane >> 4;
  const int c    = w * 16 + r16;

  const float* wrow = UeW + (size_t)c * 64 + 8 * g;
  bf16x8 bF0 = cvt8(ld4(wrow),      ld4(wrow + 4));
  bf16x8 bF1 = cvt8(ld4(wrow + 32), ld4(wrow + 36));

  const float* Vxe = ws + WS_VXE;
  const float ueb  = Ueb[c];
  const float vxei = Vxe[(size_t)bi * 64 + c];

  // BN coefficients for channel c
  float mean = ws[WS_ESUM + c] * INV_EDGE_CNT;
  float var  = ws[WS_ESQ  + c] * INV_EDGE_CNT - mean * mean;
  float sc = rsqrtf(var + EPSBN) * bneg[c];
  float sh = bneb[c] - mean * sc;

  const float* eTile = e + (size_t)bi * (Nv * Hv);
  const float* eb = eTile + (size_t)r16 * 64 + 8 * g;
  float* oTile = eOut + (size_t)bi * (Nv * Hv);

  for (int jt = 0; jt < 16; ++jt) {
    const float* ep = eb + jt * (16 * 64);
    bf16x8 aF0 = cvt8(ld4(ep),      ld4(ep + 4));
    bf16x8 aF1 = cvt8(ld4(ep + 32), ld4(ep + 36));
    f32x4 acc = {0.f, 0.f, 0.f, 0.f};
    acc = __builtin_amdgcn_mfma_f32_16x16x32_bf16(aF0, bF0, acc, 0, 0, 0);
    acc = __builtin_amdgcn_mfma_f32_16x16x32_bf16(aF1, bF1, acc, 0, 0, 0);

    const int j0 = jt * 16 + 4 * g;
#pragma unroll
    for (int r = 0; r < 4; ++r) {
      const int j = j0 + r;
      float vj = Vxe[(size_t)(rowB + j) * 64 + c];
      float t  = acc[r] + ueb + vxei + vj;
      float y  = fmaf(t, sc, sh);
      float eo = eTile[(size_t)j * 64 + c];   // residual (L1/L2 hot)
      oTile[(size_t)j * 64 + c] = fmaxf(y, 0.f) + eo;
    }
  }
}

// ---------------------------------------------------------------------------
extern "C" void kernel_launch(void* const* d_in, const int* in_sizes, int n_in,
                              void* d_out, int out_size, void* d_ws, size_t ws_size,
                              hipStream_t stream)
{
  const float* x    = (const float*)d_in[0];
  const float* e    = (const float*)d_in[1];
  const float* UeW  = (const float*)d_in[2];
  const float* Ueb  = (const float*)d_in[3];
  const float* VeW  = (const float*)d_in[4];
  const float* Veb  = (const float*)d_in[5];
  const float* UnW  = (const float*)d_in[6];
  const float* Unb  = (const float*)d_in[7];
  const float* VnW  = (const float*)d_in[8];
  const float* Vnb  = (const float*)d_in[9];
  const float* bneg = (const float*)d_in[10];
  const float* bneb = (const float*)d_in[11];
  const float* bnng = (const float*)d_in[12];
  const float* bnnb = (const float*)d_in[13];

  float* ws   = (float*)d_ws;
  float* xOut = (float*)d_out;
  float* eOut = (float*)d_out + (size_t)ROWS * Hv;

  hipMemsetAsync(ws + WS_ESUM, 0, 128 * sizeof(float), stream);

  k_lin<<<512, 256, 0, stream>>>(x, VeW, Veb, UnW, Unb, VnW, Vnb, ws);
  k_edgeA<<<ROWS, 256, 0, stream>>>(e, UeW, Ueb, ws);
  k_node<<<Hv, 256, 0, stream>>>(x, bnng, bnnb, ws, xOut);
  k_edgeC<<<ROWS, 256, 0, stream>>>(e, UeW, Ueb, bneg, bneb, ws, eOut);
}

// Round 3
// 193.344 us; speedup vs baseline: 1.8116x; 1.0568x over previous
//
#include <hip/hip_runtime.h>
#include <cstddef>
#include <cstdint>

// Problem constants (B,N,H) = (8,256,64)
constexpr int Bv = 8, Nv = 256, Hv = 64;
constexpr int ROWS = Bv * Nv;            // 2048
constexpr float INV_EDGE_CNT = 1.0f / (8.0f * 256.0f * 256.0f);
constexpr float INV_NODE_CNT = 1.0f / 2048.0f;
constexpr float EPSBN = 1e-5f;

// ws layout (float offsets)
constexpr size_t WS_VXE  = 0;          // [2048*64]
constexpr size_t WS_UX   = 131072;     // [2048*64]
constexpr size_t WS_VXN  = 262144;     // [2048*64]
constexpr size_t WS_AGG  = 393216;     // [2048*64]
constexpr size_t WS_ESUM = 524288;     // [64] -> k_node rewrites as edge-BN scale
constexpr size_t WS_ESQ  = 524352;     // [64] -> k_node rewrites as edge-BN shift

typedef __bf16 bf16x8 __attribute__((ext_vector_type(8)));
typedef float  f32x4  __attribute__((ext_vector_type(4)));

__device__ __forceinline__ float4 ld4(const float* p) {
  return *reinterpret_cast<const float4*>(p);
}

__device__ __forceinline__ bf16x8 cvt8(float4 a, float4 b) {
  bf16x8 r;
  r[0] = (__bf16)a.x; r[1] = (__bf16)a.y; r[2] = (__bf16)a.z; r[3] = (__bf16)a.w;
  r[4] = (__bf16)b.x; r[5] = (__bf16)b.y; r[6] = (__bf16)b.z; r[7] = (__bf16)b.w;
  return r;
}

#define DOT4(acc, a, b) \
  acc = fmaf((a).x, (b).x, fmaf((a).y, (b).y, fmaf((a).z, (b).z, fmaf((a).w, (b).w, acc))))

// ---------------------------------------------------------------------------
// Small linears: Vxe / Ux / Vxn  (2048 rows x 64 ch each)
__global__ __launch_bounds__(256) void k_lin(
    const float* __restrict__ x,
    const float* __restrict__ VeW, const float* __restrict__ Veb,
    const float* __restrict__ UnW, const float* __restrict__ Unb,
    const float* __restrict__ VnW, const float* __restrict__ Vnb,
    float* __restrict__ ws)
{
  int idx = blockIdx.x * 256 + threadIdx.x;   // 131072 total
  int r = idx >> 6, o = idx & 63;
  const float4* x4  = (const float4*)(x + (size_t)r * 64);
  const float4* w14 = (const float4*)(VeW + (size_t)o * 64);
  const float4* w24 = (const float4*)(UnW + (size_t)o * 64);
  const float4* w34 = (const float4*)(VnW + (size_t)o * 64);
  float a1 = 0.f, a2 = 0.f, a3 = 0.f;
#pragma unroll
  for (int h = 0; h < 16; ++h) {
    float4 xv = x4[h];
    float4 v1 = w14[h]; DOT4(a1, xv, v1);
    float4 v2 = w24[h]; DOT4(a2, xv, v2);
    float4 v3 = w34[h]; DOT4(a3, xv, v3);
  }
  ws[WS_VXE + idx] = a1 + Veb[o];
  ws[WS_UX  + idx] = a2 + Unb[o];
  ws[WS_VXN + idx] = a3 + Vnb[o];
}

// ---------------------------------------------------------------------------
// Pass A: e_tmp = e@UeW^T + b + Vxe_i + Vxe_j via MFMA(W,e) (transposed C);
// wave w owns j-rows [64w, 64w+64), ALL 64 channels. Fused sigmoid-gate
// aggregation + BN stats, block-reduced through LDS.
__global__ __launch_bounds__(256) void k_edgeA(
    const float* __restrict__ e,
    const float* __restrict__ UeW, const float* __restrict__ Ueb,
    float* __restrict__ ws)
{
  __shared__ float redL[3 * 256];

  const int tid  = threadIdx.x;
  const int lane = tid & 63;
  const int w    = tid >> 6;            // wave id -> j-range
  const int bi   = blockIdx.x;          // b*256 + i
  const int rowB = bi & ~255;
  const int r16  = lane & 15;
  const int g    = lane >> 4;

  // W fragments as MFMA "A" operand: lane holds W[16t+r16][8g..8g+7] (+k-half)
  bf16x8 wF0[4], wF1[4];
#pragma unroll
  for (int t = 0; t < 4; ++t) {
    const float* wrow = UeW + (size_t)(t * 16 + r16) * 64 + 8 * g;
    wF0[t] = cvt8(ld4(wrow),      ld4(wrow + 4));
    wF1[t] = cvt8(ld4(wrow + 32), ld4(wrow + 36));
  }

  const float* Vxe = ws + WS_VXE;
  const float* Vxn = ws + WS_VXN;

  // per-lane channel block: c = 16t + 4g + r  (r = acc reg index)
  float4 ueb4[4], vxei4[4];
#pragma unroll
  for (int t = 0; t < 4; ++t) {
    ueb4[t]  = ld4(Ueb + t * 16 + 4 * g);
    vxei4[t] = ld4(Vxe + (size_t)bi * 64 + t * 16 + 4 * g);
  }

  float sS[4][4] = {}, sQ[4][4] = {}, sA[4][4] = {};

  const float* eTile = e + (size_t)bi * (Nv * Hv);

#pragma unroll
  for (int q = 0; q < 4; ++q) {
    const int j = w * 64 + q * 16 + r16;         // this lane's j row
    const float* ep = eTile + (size_t)j * 64 + 8 * g;
    bf16x8 aF0 = cvt8(ld4(ep),      ld4(ep + 4));
    bf16x8 aF1 = cvt8(ld4(ep + 32), ld4(ep + 36));

    f32x4 acc[4];
#pragma unroll
    for (int t = 0; t < 4; ++t) {
      f32x4 z = {0.f, 0.f, 0.f, 0.f};
      acc[t] = __builtin_amdgcn_mfma_f32_16x16x32_bf16(wF0[t], aF0, z, 0, 0, 0);
      acc[t] = __builtin_amdgcn_mfma_f32_16x16x32_bf16(wF1[t], aF1, acc[t], 0, 0, 0);
    }

    const size_t jrow = (size_t)(rowB + j) * 64;
#pragma unroll
    for (int t = 0; t < 4; ++t) {
      float4 vj4 = ld4(Vxe + jrow + t * 16 + 4 * g);
      float4 vn4 = ld4(Vxn + jrow + t * 16 + 4 * g);
      float vj[4] = {vj4.x, vj4.y, vj4.z, vj4.w};
      float vn[4] = {vn4.x, vn4.y, vn4.z, vn4.w};
      float ub[4] = {ueb4[t].x, ueb4[t].y, ueb4[t].z, ueb4[t].w};
      float vi[4] = {vxei4[t].x, vxei4[t].y, vxei4[t].z, vxei4[t].w};
#pragma unroll
      for (int r = 0; r < 4; ++r) {
        float tv = acc[t][r] + ub[r] + vi[r] + vj[r];
        sS[t][r] += tv;
        sQ[t][r]  = fmaf(tv, tv, sQ[t][r]);
        float sg  = __builtin_amdgcn_rcpf(1.0f + __expf(-tv));
        sA[t][r]  = fmaf(sg, vn[r], sA[t][r]);
      }
    }
  }

  // reduce over the 16 j-lanes (bits 0..3 of lane)
#pragma unroll
  for (int t = 0; t < 4; ++t)
#pragma unroll
    for (int r = 0; r < 4; ++r) {
#pragma unroll
      for (int m = 1; m < 16; m <<= 1) {
        sS[t][r] += __shfl_xor(sS[t][r], m);
        sQ[t][r] += __shfl_xor(sQ[t][r], m);
        sA[t][r] += __shfl_xor(sA[t][r], m);
      }
    }

  if (r16 == 0) {
#pragma unroll
    for (int t = 0; t < 4; ++t) {
      int cb = w * 64 + t * 16 + 4 * g;
      *(float4*)(&redL[cb])       = make_float4(sA[t][0], sA[t][1], sA[t][2], sA[t][3]);
      *(float4*)(&redL[256 + cb]) = make_float4(sS[t][0], sS[t][1], sS[t][2], sS[t][3]);
      *(float4*)(&redL[512 + cb]) = make_float4(sQ[t][0], sQ[t][1], sQ[t][2], sQ[t][3]);
    }
  }
  __syncthreads();
  if (tid < 64) {
    const int c = tid;
    float a = redL[c] + redL[64 + c] + redL[128 + c] + redL[192 + c];
    ws[WS_AGG + (size_t)bi * 64 + c] = a;
    float s = redL[256 + c] + redL[320 + c] + redL[384 + c] + redL[448 + c];
    atomicAdd(&ws[WS_ESUM + c], s);
    float qq = redL[512 + c] + redL[576 + c] + redL[640 + c] + redL[704 + c];
    atomicAdd(&ws[WS_ESQ + c], qq);
  }
}

// ---------------------------------------------------------------------------
// Node path: x_tmp = Ux + agg ; BN over (B,N) per channel ; relu + residual.
// Thread 0 also folds the edge-BN stats into scale/shift (in-place).
__global__ __launch_bounds__(256) void k_node(
    const float* __restrict__ x,
    const float* __restrict__ bnng, const float* __restrict__ bnnb,
    const float* __restrict__ bneg, const float* __restrict__ bneb,
    float* __restrict__ ws, float* __restrict__ xOut)
{
  const int c = blockIdx.x;
  const int tid = threadIdx.x;

  if (tid == 0) {   // fold edge BN stats -> scale/shift for k_edgeC
    float mean = ws[WS_ESUM + c] * INV_EDGE_CNT;
    float var  = ws[WS_ESQ  + c] * INV_EDGE_CNT - mean * mean;
    float sc = rsqrtf(var + EPSBN) * bneg[c];
    ws[WS_ESUM + c] = sc;
    ws[WS_ESQ  + c] = bneb[c] - mean * sc;
  }

  const float* Ux  = ws + WS_UX;
  const float* agg = ws + WS_AGG;

  float v[8];
  float s = 0.f, q = 0.f;
#pragma unroll
  for (int k = 0; k < 8; ++k) {
    int r = tid + 256 * k;
    float t = Ux[(size_t)r * 64 + c] + agg[(size_t)r * 64 + c];
    v[k] = t;
    s += t;
    q = fmaf(t, t, q);
  }
#pragma unroll
  for (int m = 1; m < 64; m <<= 1) {
    s += __shfl_xor(s, m);
    q += __shfl_xor(q, m);
  }
  __shared__ float ss[4], qq[4];
  int w = tid >> 6;
  if ((tid & 63) == 0) { ss[w] = s; qq[w] = q; }
  __syncthreads();
  float S = ss[0] + ss[1] + ss[2] + ss[3];
  float Q = qq[0] + qq[1] + qq[2] + qq[3];
  float mean = S * INV_NODE_CNT;
  float var  = Q * INV_NODE_CNT - mean * mean;
  float scv = rsqrtf(var + EPSBN) * bnng[c];
  float shv = bnnb[c] - mean * scv;
#pragma unroll
  for (int k = 0; k < 8; ++k) {
    int r = tid + 256 * k;
    float y = fmaf(v[k], scv, shv);
    xOut[(size_t)r * 64 + c] = fmaxf(y, 0.f) + x[(size_t)r * 64 + c];
  }
}

// ---------------------------------------------------------------------------
// Pass C: recompute e_tmp via MFMA (same schedule as A), apply edge BN
// (prefolded scale/shift) + relu + residual, float4 stores.
__global__ __launch_bounds__(256) void k_edgeC(
    const float* __restrict__ e,
    const float* __restrict__ UeW, const float* __restrict__ Ueb,
    const float* __restrict__ ws, float* __restrict__ eOut)
{
  const int tid  = threadIdx.x;
  const int lane = tid & 63;
  const int w    = tid >> 6;
  const int bi   = blockIdx.x;
  const int rowB = bi & ~255;
  const int r16  = lane & 15;
  const int g    = lane >> 4;

  bf16x8 wF0[4], wF1[4];
#pragma unroll
  for (int t = 0; t < 4; ++t) {
    const float* wrow = UeW + (size_t)(t * 16 + r16) * 64 + 8 * g;
    wF0[t] = cvt8(ld4(wrow),      ld4(wrow + 4));
    wF1[t] = cvt8(ld4(wrow + 32), ld4(wrow + 36));
  }

  const float* Vxe = ws + WS_VXE;

  float4 ueb4[4], vxei4[4], sc4[4], sh4[4];
#pragma unroll
  for (int t = 0; t < 4; ++t) {
    ueb4[t]  = ld4(Ueb + t * 16 + 4 * g);
    vxei4[t] = ld4(Vxe + (size_t)bi * 64 + t * 16 + 4 * g);
    sc4[t]   = ld4(ws + WS_ESUM + t * 16 + 4 * g);
    sh4[t]   = ld4(ws + WS_ESQ  + t * 16 + 4 * g);
  }

  const float* eTile = e + (size_t)bi * (Nv * Hv);
  float* oTile = eOut + (size_t)bi * (Nv * Hv);

#pragma unroll
  for (int q = 0; q < 4; ++q) {
    const int j = w * 64 + q * 16 + r16;
    const float* ep = eTile + (size_t)j * 64 + 8 * g;
    bf16x8 aF0 = cvt8(ld4(ep),      ld4(ep + 4));
    bf16x8 aF1 = cvt8(ld4(ep + 32), ld4(ep + 36));

    f32x4 acc[4];
#pragma unroll
    for (int t = 0; t < 4; ++t) {
      f32x4 z = {0.f, 0.f, 0.f, 0.f};
      acc[t] = __builtin_amdgcn_mfma_f32_16x16x32_bf16(wF0[t], aF0, z, 0, 0, 0);
      acc[t] = __builtin_amdgcn_mfma_f32_16x16x32_bf16(wF1[t], aF1, acc[t], 0, 0, 0);
    }

    const size_t jrow = (size_t)(rowB + j) * 64;
#pragma unroll
    for (int t = 0; t < 4; ++t) {
      const int cb = t * 16 + 4 * g;
      float4 vj4  = ld4(Vxe + jrow + cb);
      float4 res4 = ld4(eTile + (size_t)j * 64 + cb);
      float vj[4] = {vj4.x, vj4.y, vj4.z, vj4.w};
      float rs[4] = {res4.x, res4.y, res4.z, res4.w};
      float ub[4] = {ueb4[t].x, ueb4[t].y, ueb4[t].z, ueb4[t].w};
      float vi[4] = {vxei4[t].x, vxei4[t].y, vxei4[t].z, vxei4[t].w};
      float sc[4] = {sc4[t].x, sc4[t].y, sc4[t].z, sc4[t].w};
      float sh[4] = {sh4[t].x, sh4[t].y, sh4[t].z, sh4[t].w};
      float out[4];
#pragma unroll
      for (int r = 0; r < 4; ++r) {
        float tv = acc[t][r] + ub[r] + vi[r] + vj[r];
        float y  = fmaf(tv, sc[r], sh[r]);
        out[r] = fmaxf(y, 0.f) + rs[r];
      }
      *(float4*)(oTile + (size_t)j * 64 + cb) =
          make_float4(out[0], out[1], out[2], out[3]);
    }
  }
}

// ---------------------------------------------------------------------------
extern "C" void kernel_launch(void* const* d_in, const int* in_sizes, int n_in,
                              void* d_out, int out_size, void* d_ws, size_t ws_size,
                              hipStream_t stream)
{
  const float* x    = (const float*)d_in[0];
  const float* e    = (const float*)d_in[1];
  const float* UeW  = (const float*)d_in[2];
  const float* Ueb  = (const float*)d_in[3];
  const float* VeW  = (const float*)d_in[4];
  const float* Veb  = (const float*)d_in[5];
  const float* UnW  = (const float*)d_in[6];
  const float* Unb  = (const float*)d_in[7];
  const float* VnW  = (const float*)d_in[8];
  const float* Vnb  = (const float*)d_in[9];
  const float* bneg = (const float*)d_in[10];
  const float* bneb = (const float*)d_in[11];
  const float* bnng = (const float*)d_in[12];
  const float* bnnb = (const float*)d_in[13];

  float* ws   = (float*)d_ws;
  float* xOut = (float*)d_out;
  float* eOut = (float*)d_out + (size_t)ROWS * Hv;

  hipMemsetAsync(ws + WS_ESUM, 0, 128 * sizeof(float), stream);

  k_lin<<<512, 256, 0, stream>>>(x, VeW, Veb, UnW, Unb, VnW, Vnb, ws);
  k_edgeA<<<ROWS, 256, 0, stream>>>(e, UeW, Ueb, ws);
  k_node<<<Hv, 256, 0, stream>>>(x, bnng, bnnb, bneg, bneb, ws, xOut);
  k_edgeC<<<ROWS, 256, 0, stream>>>(e, UeW, Ueb, ws, eOut);
}

// Round 4
// 168.580 us; speedup vs baseline: 2.0778x; 1.1469x over previous
//
#include <hip/hip_runtime.h>
#include <cstddef>
#include <cstdint>

// Problem constants (B,N,H) = (8,256,64)
constexpr int Bv = 8, Nv = 256, Hv = 64;
constexpr int ROWS = Bv * Nv;            // 2048
constexpr float INV_EDGE_CNT = 1.0f / (8.0f * 256.0f * 256.0f);
constexpr float INV_NODE_CNT = 1.0f / 2048.0f;
constexpr float EPSBN = 1e-5f;

// ws layout (float offsets)
constexpr size_t WS_VXE  = 0;          // [2048*64] PACKED [b][jt][t][lane][4]
constexpr size_t WS_VXN  = 131072;     // [2048*64] PACKED
constexpr size_t WS_UX   = 262144;     // [2048*64] linear [r][c]
constexpr size_t WS_AGG  = 393216;     // [2048*64] linear [r][c]
constexpr size_t WS_ESUM = 524288;     // [64] -> k_node folds to edge-BN scale
constexpr size_t WS_ESQ  = 524352;     // [64] -> k_node folds to edge-BN shift

typedef __bf16 bf16x8 __attribute__((ext_vector_type(8)));
typedef float  f32x4  __attribute__((ext_vector_type(4)));

__device__ __forceinline__ float4 ld4(const float* p) {
  return *reinterpret_cast<const float4*>(p);
}

__device__ __forceinline__ bf16x8 cvt8(float4 a, float4 b) {
  bf16x8 r;
  r[0] = (__bf16)a.x; r[1] = (__bf16)a.y; r[2] = (__bf16)a.z; r[3] = (__bf16)a.w;
  r[4] = (__bf16)b.x; r[5] = (__bf16)b.y; r[6] = (__bf16)b.z; r[7] = (__bf16)b.w;
  return r;
}

// async global->LDS 16B copy: lds dst is wave-uniform base + lane*16
__device__ __forceinline__ void async_cp16(const float* src, float* ldsDst) {
  __builtin_amdgcn_global_load_lds(
      (__attribute__((address_space(1))) void*)src,
      (__attribute__((address_space(3))) void*)ldsDst, 16, 0, 0);
}

#define DOT4(acc, a, b) \
  acc = fmaf((a).x, (b).x, fmaf((a).y, (b).y, fmaf((a).z, (b).z, fmaf((a).w, (b).w, acc))))

// ---------------------------------------------------------------------------
// Linears: Vxe / Vxn written PACKED for the edge-kernel epilogue lane order;
// Ux written linear for k_node. Thread = (row, t, g) -> 4 channels.
__global__ __launch_bounds__(256) void k_lin(
    const float* __restrict__ x,
    const float* __restrict__ VeW, const float* __restrict__ Veb,
    const float* __restrict__ UnW, const float* __restrict__ Unb,
    const float* __restrict__ VnW, const float* __restrict__ Vnb,
    float* __restrict__ ws)
{
  const int idx = blockIdx.x * 256 + threadIdx.x;   // 32768 total
  const int r  = idx >> 4;           // row 0..2047
  const int tg = idx & 15;
  const int t  = tg >> 2, g = tg & 3;
  const int c0 = t * 16 + g * 4;

  const float4* x4 = (const float4*)(x + (size_t)r * 64);
  float a1[4] = {}, a2[4] = {}, a3[4] = {};
#pragma unroll
  for (int h = 0; h < 16; ++h) {
    float4 xv = x4[h];
#pragma unroll
    for (int cc = 0; cc < 4; ++cc) {
      float4 w1 = ld4(VeW + (size_t)(c0 + cc) * 64 + h * 4); DOT4(a1[cc], xv, w1);
      float4 w2 = ld4(UnW + (size_t)(c0 + cc) * 64 + h * 4); DOT4(a2[cc], xv, w2);
      float4 w3 = ld4(VnW + (size_t)(c0 + cc) * 64 + h * 4); DOT4(a3[cc], xv, w3);
    }
  }

  const int b = r >> 8, jt = (r >> 4) & 15, r16 = r & 15;
  const size_t pidx = ((size_t)((b * 16 + jt) * 4 + t)) * 256 + (g * 16 + r16) * 4;
  *(float4*)(&ws[WS_VXE + pidx]) =
      make_float4(a1[0] + Veb[c0], a1[1] + Veb[c0 + 1], a1[2] + Veb[c0 + 2], a1[3] + Veb[c0 + 3]);
  *(float4*)(&ws[WS_VXN + pidx]) =
      make_float4(a3[0] + Vnb[c0], a3[1] + Vnb[c0 + 1], a3[2] + Vnb[c0 + 2], a3[3] + Vnb[c0 + 3]);
  *(float4*)(&ws[WS_UX + (size_t)r * 64 + c0]) =
      make_float4(a2[0] + Unb[c0], a2[1] + Unb[c0 + 1], a2[2] + Unb[c0 + 2], a2[3] + Unb[c0 + 3]);
}

// ---------------------------------------------------------------------------
// Pass A: e_tmp = e@UeW^T + b + Vxe_i + Vxe_j via MFMA(W,e); wave w owns
// j-rows [64w,64w+64). e staged per-wave into LDS via global_load_lds with
// source-swizzled chunks (LDS[r][p] = e[r][p ^ (r&7)]); epilogue reads packed.
__global__ __launch_bounds__(256) void k_edgeA(
    const float* __restrict__ e,
    const float* __restrict__ UeW, const float* __restrict__ Ueb,
    float* __restrict__ ws)
{
  __shared__ __align__(16) float eL[4 * 2048];   // 4 waves x 32 rows x 64 = 32KB
  __shared__ float redL[3 * 256];

  const int tid  = threadIdx.x;
  const int lane = tid & 63;
  const int w    = tid >> 6;
  const int bi   = blockIdx.x;
  const int b    = bi >> 8;
  const int r16  = lane & 15;
  const int g    = lane >> 4;

  const float* eTile = e + (size_t)bi * (Nv * Hv);
  float* myBuf = &eL[w * 2048];

  // W fragments (A-operand): lane holds W[16t+r16][8g..8g+7] / [+32..]
  bf16x8 wF0[4], wF1[4];
#pragma unroll
  for (int t = 0; t < 4; ++t) {
    const float* wrow = UeW + (size_t)(t * 16 + r16) * 64 + 8 * g;
    wF0[t] = cvt8(ld4(wrow),      ld4(wrow + 4));
    wF1[t] = cvt8(ld4(wrow + 32), ld4(wrow + 36));
  }

  const float* VXEP = ws + WS_VXE;
  const float* VXNP = ws + WS_VXN;

  const int jti = (bi >> 4) & 15, r16i = bi & 15;
  float4 ueb4[4], vxei4[4];
#pragma unroll
  for (int t = 0; t < 4; ++t) {
    ueb4[t]  = ld4(Ueb + t * 16 + 4 * g);
    vxei4[t] = ld4(VXEP + ((size_t)((b * 16 + jti) * 4 + t)) * 256 + (g * 16 + r16i) * 4);
  }

  float sS[4][4] = {}, sQ[4][4] = {}, sA[4][4] = {};

  for (int h = 0; h < 2; ++h) {
    // stage rows [64w+32h, +32): 8 x 1KB contiguous, source chunk-swizzled
#pragma unroll
    for (int k = 0; k < 8; ++k) {
      const int m  = k * 64 + lane;
      const int rl = m >> 4;            // 0..31
      const int p  = m & 15;
      const int c  = p ^ (rl & 7);
      const float* src = eTile + (size_t)(w * 64 + h * 32 + rl) * 64 + c * 4;
      async_cp16(src, myBuf + k * 256);
    }
    asm volatile("s_waitcnt vmcnt(0)" ::: "memory");

#pragma unroll
    for (int q2 = 0; q2 < 2; ++q2) {
      const int q  = h * 2 + q2;
      const int rl = q2 * 16 + r16;
      const float* rbase = myBuf + rl * 64;
      const int sw = rl & 7;

      // packed epilogue loads (independent of MFMA; lane-linear 1KB/inst)
      const size_t pb = (size_t)((b * 16 + (w * 4 + q)) * 4);
      float4 vj4[4], vn4[4];
#pragma unroll
      for (int t = 0; t < 4; ++t) {
        vj4[t] = ld4(VXEP + (pb + t) * 256 + lane * 4);
        vn4[t] = ld4(VXNP + (pb + t) * 256 + lane * 4);
      }

      float4 f0 = ld4(rbase + (((2 * g)     ^ sw) << 2));
      float4 f1 = ld4(rbase + (((2 * g + 1) ^ sw) << 2));
      float4 f2 = ld4(rbase + ((((2 * g) ^ sw) + 8) << 2));
      float4 f3 = ld4(rbase + ((((2 * g + 1) ^ sw) + 8) << 2));
      bf16x8 aF0 = cvt8(f0, f1);
      bf16x8 aF1 = cvt8(f2, f3);

      f32x4 acc[4];
#pragma unroll
      for (int t = 0; t < 4; ++t) {
        f32x4 z = {0.f, 0.f, 0.f, 0.f};
        acc[t] = __builtin_amdgcn_mfma_f32_16x16x32_bf16(wF0[t], aF0, z, 0, 0, 0);
        acc[t] = __builtin_amdgcn_mfma_f32_16x16x32_bf16(wF1[t], aF1, acc[t], 0, 0, 0);
      }

#pragma unroll
      for (int t = 0; t < 4; ++t) {
        float vj[4] = {vj4[t].x, vj4[t].y, vj4[t].z, vj4[t].w};
        float vn[4] = {vn4[t].x, vn4[t].y, vn4[t].z, vn4[t].w};
        float ub[4] = {ueb4[t].x, ueb4[t].y, ueb4[t].z, ueb4[t].w};
        float vi[4] = {vxei4[t].x, vxei4[t].y, vxei4[t].z, vxei4[t].w};
#pragma unroll
        for (int r = 0; r < 4; ++r) {
          float tv = acc[t][r] + ub[r] + vi[r] + vj[r];
          sS[t][r] += tv;
          sQ[t][r]  = fmaf(tv, tv, sQ[t][r]);
          float sg  = __builtin_amdgcn_rcpf(1.0f + __expf(-tv));
          sA[t][r]  = fmaf(sg, vn[r], sA[t][r]);
        }
      }
    }
  }

  // reduce over the 16 j-lanes (bits 0..3 of lane)
#pragma unroll
  for (int t = 0; t < 4; ++t)
#pragma unroll
    for (int r = 0; r < 4; ++r) {
#pragma unroll
      for (int m = 1; m < 16; m <<= 1) {
        sS[t][r] += __shfl_xor(sS[t][r], m);
        sQ[t][r] += __shfl_xor(sQ[t][r], m);
        sA[t][r] += __shfl_xor(sA[t][r], m);
      }
    }

  if (r16 == 0) {
#pragma unroll
    for (int t = 0; t < 4; ++t) {
      int cb = w * 64 + t * 16 + 4 * g;
      *(float4*)(&redL[cb])       = make_float4(sA[t][0], sA[t][1], sA[t][2], sA[t][3]);
      *(float4*)(&redL[256 + cb]) = make_float4(sS[t][0], sS[t][1], sS[t][2], sS[t][3]);
      *(float4*)(&redL[512 + cb]) = make_float4(sQ[t][0], sQ[t][1], sQ[t][2], sQ[t][3]);
    }
  }
  __syncthreads();
  if (tid < 64) {
    const int c = tid;
    float a = redL[c] + redL[64 + c] + redL[128 + c] + redL[192 + c];
    ws[WS_AGG + (size_t)bi * 64 + c] = a;
    float s = redL[256 + c] + redL[320 + c] + redL[384 + c] + redL[448 + c];
    atomicAdd(&ws[WS_ESUM + c], s);
    float qq = redL[512 + c] + redL[576 + c] + redL[640 + c] + redL[704 + c];
    atomicAdd(&ws[WS_ESQ + c], qq);
  }
}

// ---------------------------------------------------------------------------
// Node path: x_tmp = Ux + agg ; BN over (B,N) per channel ; relu + residual.
// Thread 0 folds the edge-BN stats into scale/shift (in-place).
__global__ __launch_bounds__(256) void k_node(
    const float* __restrict__ x,
    const float* __restrict__ bnng, const float* __restrict__ bnnb,
    const float* __restrict__ bneg, const float* __restrict__ bneb,
    float* __restrict__ ws, float* __restrict__ xOut)
{
  const int c = blockIdx.x;
  const int tid = threadIdx.x;

  if (tid == 0) {
    float mean = ws[WS_ESUM + c] * INV_EDGE_CNT;
    float var  = ws[WS_ESQ  + c] * INV_EDGE_CNT - mean * mean;
    float sc = rsqrtf(var + EPSBN) * bneg[c];
    ws[WS_ESUM + c] = sc;
    ws[WS_ESQ  + c] = bneb[c] - mean * sc;
  }

  const float* Ux  = ws + WS_UX;
  const float* agg = ws + WS_AGG;

  float v[8];
  float s = 0.f, q = 0.f;
#pragma unroll
  for (int k = 0; k < 8; ++k) {
    int r = tid + 256 * k;
    float t = Ux[(size_t)r * 64 + c] + agg[(size_t)r * 64 + c];
    v[k] = t;
    s += t;
    q = fmaf(t, t, q);
  }
#pragma unroll
  for (int m = 1; m < 64; m <<= 1) {
    s += __shfl_xor(s, m);
    q += __shfl_xor(q, m);
  }
  __shared__ float ss[4], qq[4];
  int w = tid >> 6;
  if ((tid & 63) == 0) { ss[w] = s; qq[w] = q; }
  __syncthreads();
  float S = ss[0] + ss[1] + ss[2] + ss[3];
  float Q = qq[0] + qq[1] + qq[2] + qq[3];
  float mean = S * INV_NODE_CNT;
  float var  = Q * INV_NODE_CNT - mean * mean;
  float scv = rsqrtf(var + EPSBN) * bnng[c];
  float shv = bnnb[c] - mean * scv;
#pragma unroll
  for (int k = 0; k < 8; ++k) {
    int r = tid + 256 * k;
    float y = fmaf(v[k], scv, shv);
    xOut[(size_t)r * 64 + c] = fmaxf(y, 0.f) + x[(size_t)r * 64 + c];
  }
}

// ---------------------------------------------------------------------------
// Pass C: recompute e_tmp via MFMA (same staged schedule), apply prefolded
// edge BN + relu + residual (residual read from the staged LDS tile).
__global__ __launch_bounds__(256) void k_edgeC(
    const float* __restrict__ e,
    const float* __restrict__ UeW, const float* __restrict__ Ueb,
    const float* __restrict__ ws, float* __restrict__ eOut)
{
  __shared__ __align__(16) float eL[4 * 2048];   // 32KB

  const int tid  = threadIdx.x;
  const int lane = tid & 63;
  const int w    = tid >> 6;
  const int bi   = blockIdx.x;
  const int b    = bi >> 8;
  const int r16  = lane & 15;
  const int g    = lane >> 4;

  const float* eTile = e + (size_t)bi * (Nv * Hv);
  float* myBuf = &eL[w * 2048];
  float* oTile = eOut + (size_t)bi * (Nv * Hv);

  bf16x8 wF0[4], wF1[4];
#pragma unroll
  for (int t = 0; t < 4; ++t) {
    const float* wrow = UeW + (size_t)(t * 16 + r16) * 64 + 8 * g;
    wF0[t] = cvt8(ld4(wrow),      ld4(wrow + 4));
    wF1[t] = cvt8(ld4(wrow + 32), ld4(wrow + 36));
  }

  const float* VXEP = ws + WS_VXE;
  const int jti = (bi >> 4) & 15, r16i = bi & 15;
  float4 ueb4[4], vxei4[4], sc4[4], sh4[4];
#pragma unroll
  for (int t = 0; t < 4; ++t) {
    ueb4[t]  = ld4(Ueb + t * 16 + 4 * g);
    vxei4[t] = ld4(VXEP + ((size_t)((b * 16 + jti) * 4 + t)) * 256 + (g * 16 + r16i) * 4);
    sc4[t]   = ld4(ws + WS_ESUM + t * 16 + 4 * g);
    sh4[t]   = ld4(ws + WS_ESQ  + t * 16 + 4 * g);
  }

  for (int h = 0; h < 2; ++h) {
#pragma unroll
    for (int k = 0; k < 8; ++k) {
      const int m  = k * 64 + lane;
      const int rl = m >> 4;
      const int p  = m & 15;
      const int c  = p ^ (rl & 7);
      const float* src = eTile + (size_t)(w * 64 + h * 32 + rl) * 64 + c * 4;
      async_cp16(src, myBuf + k * 256);
    }
    asm volatile("s_waitcnt vmcnt(0)" ::: "memory");

#pragma unroll
    for (int q2 = 0; q2 < 2; ++q2) {
      const int q  = h * 2 + q2;
      const int rl = q2 * 16 + r16;
      const float* rbase = myBuf + rl * 64;
      const int sw = rl & 7;
      const int j  = w * 64 + q * 16 + r16;

      const size_t pb = (size_t)((b * 16 + (w * 4 + q)) * 4);
      float4 vj4[4];
#pragma unroll
      for (int t = 0; t < 4; ++t)
        vj4[t] = ld4(VXEP + (pb + t) * 256 + lane * 4);

      float4 f0 = ld4(rbase + (((2 * g)     ^ sw) << 2));
      float4 f1 = ld4(rbase + (((2 * g + 1) ^ sw) << 2));
      float4 f2 = ld4(rbase + ((((2 * g) ^ sw) + 8) << 2));
      float4 f3 = ld4(rbase + ((((2 * g + 1) ^ sw) + 8) << 2));
      bf16x8 aF0 = cvt8(f0, f1);
      bf16x8 aF1 = cvt8(f2, f3);

      f32x4 acc[4];
#pragma unroll
      for (int t = 0; t < 4; ++t) {
        f32x4 z = {0.f, 0.f, 0.f, 0.f};
        acc[t] = __builtin_amdgcn_mfma_f32_16x16x32_bf16(wF0[t], aF0, z, 0, 0, 0);
        acc[t] = __builtin_amdgcn_mfma_f32_16x16x32_bf16(wF1[t], aF1, acc[t], 0, 0, 0);
      }

#pragma unroll
      for (int t = 0; t < 4; ++t) {
        // residual from staged LDS tile: chunk (4t+g) ^ sw
        float4 res4 = ld4(rbase + ((((4 * t + g) ^ sw)) << 2));
        float vj[4] = {vj4[t].x, vj4[t].y, vj4[t].z, vj4[t].w};
        float rs[4] = {res4.x, res4.y, res4.z, res4.w};
        float ub[4] = {ueb4[t].x, ueb4[t].y, ueb4[t].z, ueb4[t].w};
        float vi[4] = {vxei4[t].x, vxei4[t].y, vxei4[t].z, vxei4[t].w};
        float sc[4] = {sc4[t].x, sc4[t].y, sc4[t].z, sc4[t].w};
        float sh[4] = {sh4[t].x, sh4[t].y, sh4[t].z, sh4[t].w};
        float out[4];
#pragma unroll
        for (int r = 0; r < 4; ++r) {
          float tv = acc[t][r] + ub[r] + vi[r] + vj[r];
          float y  = fmaf(tv, sc[r], sh[r]);
          out[r] = fmaxf(y, 0.f) + rs[r];
        }
        *(float4*)(oTile + (size_t)j * 64 + t * 16 + 4 * g) =
            make_float4(out[0], out[1], out[2], out[3]);
      }
    }
  }
}

// ---------------------------------------------------------------------------
extern "C" void kernel_launch(void* const* d_in, const int* in_sizes, int n_in,
                              void* d_out, int out_size, void* d_ws, size_t ws_size,
                              hipStream_t stream)
{
  const float* x    = (const float*)d_in[0];
  const float* e    = (const float*)d_in[1];
  const float* UeW  = (const float*)d_in[2];
  const float* Ueb  = (const float*)d_in[3];
  const float* VeW  = (const float*)d_in[4];
  const float* Veb  = (const float*)d_in[5];
  const float* UnW  = (const float*)d_in[6];
  const float* Unb  = (const float*)d_in[7];
  const float* VnW  = (const float*)d_in[8];
  const float* Vnb  = (const float*)d_in[9];
  const float* bneg = (const float*)d_in[10];
  const float* bneb = (const float*)d_in[11];
  const float* bnng = (const float*)d_in[12];
  const float* bnnb = (const float*)d_in[13];

  float* ws   = (float*)d_ws;
  float* xOut = (float*)d_out;
  float* eOut = (float*)d_out + (size_t)ROWS * Hv;

  hipMemsetAsync(ws + WS_ESUM, 0, 128 * sizeof(float), stream);

  k_lin<<<128, 256, 0, stream>>>(x, VeW, Veb, UnW, Unb, VnW, Vnb, ws);
  k_edgeA<<<ROWS, 256, 0, stream>>>(e, UeW, Ueb, ws);
  k_node<<<Hv, 256, 0, stream>>>(x, bnng, bnnb, bneg, bneb, ws, xOut);
  k_edgeC<<<ROWS, 256, 0, stream>>>(e, UeW, Ueb, ws, eOut);
}